// Round 1
// baseline (355.889 us; speedup 1.0000x reference)
//
#include <hip/hip_runtime.h>
#include <hip/hip_bf16.h>
#include <cstdint>

#define NN 50000
#define TT 128
#define INF 6
#define HH 32
#define NE 2000
#define NI 150000
#define RR 16

typedef __attribute__((ext_vector_type(4)))  float f32x4;
typedef __attribute__((ext_vector_type(8)))  short short8;

__device__ __forceinline__ float lrelu(float x, float s){ return x > 0.f ? x : s*x; }

// ---- packed bf16 helpers (v_cvt_pk_bf16_f32 path) ----
__device__ __forceinline__ unsigned pk2(float a, float b){        // [bf16(a) | bf16(b)<<16]
  union { __hip_bfloat162 h; unsigned u; } t;
  t.h = __float22bfloat162_rn(make_float2(a, b));
  return t.u;
}
__device__ __forceinline__ void pkhl(float a, float b, unsigned &hi, unsigned &lo){
  hi = pk2(a, b);
  float ha = __uint_as_float(hi << 16);
  float hb = __uint_as_float(hi & 0xFFFF0000u);
  lo = pk2(a - ha, b - hb);
}
__device__ __forceinline__ unsigned pksplit(float x){             // (hi(x), lo(x)) in one u32
  unsigned h = pk2(x, 0.f) & 0xFFFFu;
  float hf = __uint_as_float(h << 16);
  unsigned l = pk2(x - hf, 0.f) & 0xFFFFu;
  return h | (l << 16);
}
__device__ __forceinline__ short8 mk8(unsigned a, unsigned b, unsigned c, unsigned d){
  union { unsigned u[4]; short8 v; } t;
  t.u[0]=a; t.u[1]=b; t.u[2]=c; t.u[3]=d;
  return t.v;
}
#define MFMA16 __builtin_amdgcn_mfma_f32_16x16x32_bf16

// =====================================================================
// GRU on mfma_f32_16x16x32_bf16. One wave = 16 nodes -> 3125 waves
// (was 1563 with 32x32 tiles): occupancy ~3 waves/SIMD so the serial
// MFMA->GUPD->pack chain of one wave hides under other waves' VALU.
// k-space permutation pi(8g+e) = (e<4 ? 4g+e : 16+4g+e-4) applied to
// W_hh/W1 COLUMNS makes each lane's D rows exactly its own B k-slots:
// next-step B = 4 pk2, ZERO shuffles (was 8 shfl + 8 sel), and the
// epilogue needs no LDS transpose for the B operand.
// 18 mfma / 16 nodes / step: per 16-row tile {x(1) + Whh_hi(1) +
// Whh_lo(1)}, K=32 = H in one chain. Gate tiles q: 0,1=r 2,3=z 4,5=n.
// B x-cell layout per timestep (8 u32): [xh01,xh23,xh45,xl01,xl23,
// xl45,(1,1),0] -> g0 reads slots 0-3, g1 slots 4-7, g2/g3 zero frag.
// exp2 folded into weights; 5-trans GUPD; two half-tile phases to
// bound live accumulators (8 x f32x4). launch_bounds(64,3): no forced
// spill, allows 3-4 waves/SIMD.
// =====================================================================
__global__ __launch_bounds__(64,3) void gru_mfma(
    const float* __restrict__ price,
    const float* __restrict__ W_ih, const float* __restrict__ W_hh,
    const float* __restrict__ b_ih, const float* __restrict__ b_hh,
    const float* __restrict__ W1,
    float* __restrict__ xw, float* __restrict__ eaccZ)
{
  __shared__ __align__(16) unsigned xs[2][1024];   // [buf][16 nodes * 64 u32] = 8 KB

  const int lane = threadIdx.x;
  const int c    = lane & 15;    // node col (also A-row index)
  const int g    = lane >> 4;    // k-group 0..3 (owns B slots 8g..8g+7)
  const int n0   = blockIdx.x*16;   // 3125 blocks, no tail (50000 = 16*3125)

  // fold eacc zeroing into this launch (runs before scat_e kernel)
  { int gt = blockIdx.x*64 + lane; if (gt < NE*HH) eaccZ[gt] = 0.f; }

  // const slots per timestep cell: slot6=(1,1)bf16, slot7=0, both buffers
  for (int idx = lane; idx < 256; idx += 64){
    int bsel = idx >> 7, rem = idx & 127;
    int nd = rem >> 3, t7 = rem & 7;
    int swz = (nd&7)<<2;
    xs[bsel][nd*64 + ((t7*8+6) ^ swz)] = 0x3F803F80u;
    xs[bsel][nd*64 + ((t7*8+7) ^ swz)] = 0u;
  }

  // ---- A fragments (k-permuted: slot 8g+e -> h-unit (e<4 ? 4g+e : 16+4g+e-4)) ----
  short8 Ax[6], Ahh[6], Ahl[6];
  f32x4 BHN[2];
#pragma unroll
  for (int q=0;q<6;q++){
    const int gr = q*16 + c;             // gate row: r=0-31, z=32-63, n=64-95
    const float sc = (q<4) ? -1.44269504f : 2.88539008f;
    const float* vi = W_ih + gr*INF;
    const float w0=vi[0]*sc, w1=vi[1]*sc, w2=vi[2]*sc, w3=vi[3]*sc, w4=vi[4]*sc, w5=vi[5]*sc;
    const float bias = (b_ih[gr] + ((q<4) ? b_hh[gr] : 0.f)) * sc;
    // x-path A: k0-5=Wh*xh, k6-11=Wh*xl, k12-13=(bh,bl)*(1,1), rest 0
    if (g==0)      Ax[q] = mk8(pk2(w0,w1), pk2(w2,w3), pk2(w4,w5), pk2(w0,w1));
    else if (g==1) Ax[q] = mk8(pk2(w2,w3), pk2(w4,w5), pksplit(bias), 0u);
    else           Ax[q] = mk8(0u,0u,0u,0u);
    // h-path A: columns {4g..4g+3} and {16+4g..16+4g+3} (pi-permuted k)
    const float* wp = W_hh + gr*HH;
    float4 wa = *(const float4*)(wp + 4*g);
    float4 wb = *(const float4*)(wp + 16 + 4*g);
    wa.x*=sc; wa.y*=sc; wa.z*=sc; wa.w*=sc;
    wb.x*=sc; wb.y*=sc; wb.z*=sc; wb.w*=sc;
    unsigned h0_,l0_,h1_,l1_,h2_,l2_,h3_,l3_;
    pkhl(wa.x,wa.y,h0_,l0_); pkhl(wa.z,wa.w,h1_,l1_);
    pkhl(wb.x,wb.y,h2_,l2_); pkhl(wb.z,wb.w,h3_,l3_);
    Ahh[q] = mk8(h0_,h1_,h2_,h3_);
    Ahl[q] = mk8(l0_,l1_,l2_,l3_);
  }
  // b_hh n-rows (scaled) in the C operand of the NH tiles
#pragma unroll
  for (int q=0;q<2;q++)
#pragma unroll
    for (int j=0;j<4;j++)
      BHN[q][j] = b_hh[2*HH + q*16 + 4*g + j] * 2.88539008f;
  const f32x4 Z4 = {0.f,0.f,0.f,0.f};

  f32x4 h0 = Z4, h1 = Z4;                 // units 4g+j (tile0), 16+4g+j (tile1)
  short8 Bh = mk8(0u,0u,0u,0u);

  // ---- staging: 16 nodes x 48 floats per chunk = 3 float4 per lane ----
  float4 ld[3];
#define PREFETCH(C) { \
  _Pragma("unroll") \
  for (int q=0;q<3;q++){ \
    int id=q*64+lane, a2=id/12, off=id%12; \
    ld[q] = *(const float4*)(price + (size_t)(n0+a2)*(TT*INF) + (C)*48 + off*4); \
  } }
#define STAGE(BUF) { \
  _Pragma("unroll") \
  for (int q=0;q<3;q++){ \
    int id=q*64+lane, a2=id/12, off=id%12; \
    int swz=(a2&7)<<2; unsigned* row=(BUF)+a2*64; \
    _Pragma("unroll") \
    for (int p=0;p<2;p++){ \
      float e0 = p? ld[q].z : ld[q].x; \
      float e1 = p? ld[q].w : ld[q].y; \
      int b = off*4 + p*2; int ttl = b/6; int ii = b - ttl*6; \
      unsigned hi_, lo_; pkhl(e0, e1, hi_, lo_); \
      row[(ttl*8 + (ii>>1)) ^ swz]     = hi_; \
      row[(ttl*8 + 3 + (ii>>1)) ^ swz] = lo_; \
    } } }

#define GUPD(hvar, AR, AZ, ANX, ANH) { \
      float er = __builtin_amdgcn_exp2f(AR); \
      float rr = __builtin_amdgcn_rcpf(1.f + er); \
      float p  = (ANX) + rr*(ANH); \
      float ez = __builtin_amdgcn_exp2f(AZ); \
      float et = __builtin_amdgcn_exp2f(p); \
      float etp = et + 1.f, etm = et - 1.f; \
      float num = hvar*etp + ez*etm; \
      float den = (1.f + ez) * etp; \
      hvar = num * __builtin_amdgcn_rcpf(den); }

  PREFETCH(0); STAGE(&xs[0][0]);

  const int swzc = (c&7)<<2;

#pragma unroll 1
  for (int ch=0; ch<16; ch++){
    if (ch<15) PREFETCH(ch+1);
    const unsigned* cell = &xs[ch&1][c*64];
    unsigned* sb = &xs[(ch&1)^1][0];
#pragma unroll 1
    for (int tt=0; tt<8; tt++){
      union{uint4 u; short8 s;} cv;
      cv.u.x=0u; cv.u.y=0u; cv.u.z=0u; cv.u.w=0u;
      if (g < 2) cv.u = *(const uint4*)(cell + ((tt*8 + 4*g) ^ swzc));
      // ---- half 0: units 0-15 (each lane: 4g+j) ----
      f32x4 aR0  = MFMA16(Ax[0], cv.s, Z4, 0,0,0);
      f32x4 aZ0  = MFMA16(Ax[2], cv.s, Z4, 0,0,0);
      f32x4 aNX0 = MFMA16(Ax[4], cv.s, Z4, 0,0,0);
      f32x4 aNH0 = MFMA16(Ahh[4], Bh, BHN[0], 0,0,0);
      aR0  = MFMA16(Ahh[0], Bh, aR0, 0,0,0);
      aR0  = MFMA16(Ahl[0], Bh, aR0, 0,0,0);
      aZ0  = MFMA16(Ahh[2], Bh, aZ0, 0,0,0);
      aZ0  = MFMA16(Ahl[2], Bh, aZ0, 0,0,0);
      aNH0 = MFMA16(Ahl[4], Bh, aNH0, 0,0,0);
#pragma unroll
      for (int j=0;j<4;j++) GUPD(h0[j], aR0[j], aZ0[j], aNX0[j], aNH0[j]);
      // ---- half 1: units 16-31 (each lane: 16+4g+j) ----
      f32x4 aR1  = MFMA16(Ax[1], cv.s, Z4, 0,0,0);
      f32x4 aZ1  = MFMA16(Ax[3], cv.s, Z4, 0,0,0);
      f32x4 aNX1 = MFMA16(Ax[5], cv.s, Z4, 0,0,0);
      f32x4 aNH1 = MFMA16(Ahh[5], Bh, BHN[1], 0,0,0);
      aR1  = MFMA16(Ahh[1], Bh, aR1, 0,0,0);
      aR1  = MFMA16(Ahl[1], Bh, aR1, 0,0,0);
      aZ1  = MFMA16(Ahh[3], Bh, aZ1, 0,0,0);
      aZ1  = MFMA16(Ahl[3], Bh, aZ1, 0,0,0);
      aNH1 = MFMA16(Ahl[5], Bh, aNH1, 0,0,0);
#pragma unroll
      for (int j=0;j<4;j++) GUPD(h1[j], aR1[j], aZ1[j], aNX1[j], aNH1[j]);
      // next-step B: pi-permutation makes lane-owned D rows == lane's B k-slots
      Bh = mk8(pk2(h0[0],h0[1]), pk2(h0[2],h0[3]), pk2(h1[0],h1[1]), pk2(h1[2],h1[3]));
    }
    if (ch<15) STAGE(sb);
  }

  // ---- epilogue: lrelu(h); xw = lrelu(h) @ W1^T (two 16-row tiles, 3-term, K=32) ----
  f32x4 l0, l1;
#pragma unroll
  for (int j=0;j<4;j++){ l0[j] = lrelu(h0[j], 0.01f); l1[j] = lrelu(h1[j], 0.01f); }
  unsigned q0,s0,q1,s1,q2,s2,q3,s3;
  pkhl(l0[0],l0[1],q0,s0); pkhl(l0[2],l0[3],q1,s1);
  pkhl(l1[0],l1[1],q2,s2); pkhl(l1[2],l1[3],q3,s3);
  short8 Brh = mk8(q0,q1,q2,q3), Brl = mk8(s0,s1,s2,s3);
  short8 W1h[2], W1l[2];
#pragma unroll
  for (int q=0;q<2;q++){
    const float* wp = W1 + (q*16 + c)*HH;    // same pi-permuted k columns
    float4 wa = *(const float4*)(wp + 4*g);
    float4 wb = *(const float4*)(wp + 16 + 4*g);
    unsigned h0_,l0_,h1_,l1_,h2_,l2_,h3_,l3_;
    pkhl(wa.x,wa.y,h0_,l0_); pkhl(wa.z,wa.w,h1_,l1_);
    pkhl(wb.x,wb.y,h2_,l2_); pkhl(wb.z,wb.w,h3_,l3_);
    W1h[q] = mk8(h0_,h1_,h2_,h3_);
    W1l[q] = mk8(l0_,l1_,l2_,l3_);
  }
  f32x4 o0 = MFMA16(W1h[0], Brh, Z4, 0,0,0);
  o0 = MFMA16(W1l[0], Brh, o0, 0,0,0);
  o0 = MFMA16(W1h[0], Brl, o0, 0,0,0);
  f32x4 o1 = MFMA16(W1h[1], Brh, Z4, 0,0,0);
  o1 = MFMA16(W1l[1], Brh, o1, 0,0,0);
  o1 = MFMA16(W1h[1], Brl, o1, 0,0,0);
  // transpose via LDS (same wave, ordered) and store coalesced
  float* ldsF = (float*)&xs[0][0];
#pragma unroll
  for (int j=0;j<4;j++){
    ldsF[c*33 + 4*g + j]      = o0[j];
    ldsF[c*33 + 16 + 4*g + j] = o1[j];
  }
  {
    int nn = lane>>2, f0 = (lane&3)*8;
    float4 v0, v1;
    v0.x = ldsF[nn*33 + f0 + 0]; v0.y = ldsF[nn*33 + f0 + 1];
    v0.z = ldsF[nn*33 + f0 + 2]; v0.w = ldsF[nn*33 + f0 + 3];
    v1.x = ldsF[nn*33 + f0 + 4]; v1.y = ldsF[nn*33 + f0 + 5];
    v1.z = ldsF[nn*33 + f0 + 6]; v1.w = ldsF[nn*33 + f0 + 7];
    *(float4*)(xw + (size_t)(n0+nn)*HH + f0)     = v0;
    *(float4*)(xw + (size_t)(n0+nn)*HH + f0 + 4) = v1;
  }
}

// ---------------- scatter xw -> edge accumulators (+degree count on 1st pass) ----------------
template<bool COUNT>
__global__ __launch_bounds__(256) void scat_e(const float* __restrict__ xw, const int* __restrict__ nidx,
                                              const int* __restrict__ eidx, float* __restrict__ eacc,
                                              float* __restrict__ degD, float* __restrict__ degB){
  int idx = blockIdx.x*256 + threadIdx.x;   // NI*32 exact
  int i = idx >> 5, f = idx & 31;
  int nd = nidx[i], e = eidx[i];
  if (COUNT && f == 0){
    atomicAdd(&degD[nd], 1.f);
    atomicAdd(&degB[e], 1.f);
  }
  atomicAdd(&eacc[(size_t)e*HH + f], xw[(size_t)nd*HH + f]);
}
template __global__ void scat_e<true>(const float*, const int*, const int*, float*, float*, float*);
template __global__ void scat_e<false>(const float*, const int*, const int*, float*, float*, float*);

// ---------------- gather edge means -> node accumulators ----------------
__global__ __launch_bounds__(256) void scat_n(const float* __restrict__ eacc, const float* __restrict__ degB,
                                              const int* __restrict__ nidx, const int* __restrict__ eidx,
                                              float* __restrict__ nacc){
  int idx = blockIdx.x*256 + threadIdx.x;   // NI*32 exact
  int i = idx >> 5, f = idx & 31;
  int nd = nidx[i], e = eidx[i];
  float b = degB[e];
  float binv = b > 0.f ? 1.f/b : 0.f;
  atomicAdd(&nacc[(size_t)nd*HH + f], eacc[(size_t)e*HH + f]*binv);
}

// ---------------- x1 = leaky(nacc*Dinv + b, .2); Y = x1 @ W^T; nacc:=0; eacc:=0 ----------------
__global__ __launch_bounds__(256) void finmm(float* __restrict__ nacc, const float* __restrict__ degD,
                                             const float* __restrict__ bias, const float* __restrict__ W,
                                             float* __restrict__ Y, float* __restrict__ eacc){
  __shared__ float sWt[HH*HH];
  __shared__ float sX[8*HH];
  int tid = threadIdx.x;
  if (blockIdx.x < 250) eacc[blockIdx.x*256 + tid] = 0.f;   // re-zero for conv2 (250*256 = 64000)
  int f0 = tid>>5, k = tid&31;
#pragma unroll
  for (int q=0;q<4;q++) sWt[k*HH + (q*8+f0)] = W[(q*8+f0)*HH + k];
  size_t base = (size_t)blockIdx.x*8*HH;
  int n = blockIdx.x*8 + (tid>>5);
  float d = degD[n];
  float dinv = d > 0.f ? 1.f/d : 0.f;
  sX[tid] = lrelu(nacc[base + tid]*dinv + bias[tid&31], 0.2f);
  nacc[base + tid] = 0.f;   // reset for conv2
  __syncthreads();
  float a = 0.f;
#pragma unroll
  for (int kk=0;kk<HH;kk++) a += sX[(tid>>5)*HH+kk]*sWt[kk*HH+(tid&31)];
  Y[base + tid] = a;
}

// ---------------- x2 = leaky(nacc*Dinv + b2, .2); out = leaky(x2@Wl^T + bl, .01) ----------------
__global__ __launch_bounds__(256) void fin_final(const float* __restrict__ nacc, const float* __restrict__ degD,
                                                 const float* __restrict__ b2, const float* __restrict__ Wl,
                                                 const float* __restrict__ bl, float* __restrict__ out){
  __shared__ float sWl[HH*RR];
  __shared__ float sX[8*HH];
  int tid = threadIdx.x;
#pragma unroll
  for (int q=0;q<2;q++){
    int idx = q*256 + tid;        // 512 = RR*HH
    int r = idx >> 5, kk = idx & 31;
    sWl[kk*RR + r] = Wl[idx];
  }
  size_t base = (size_t)blockIdx.x*8*HH;
  int n = blockIdx.x*8 + (tid>>5);
  float d = degD[n];
  float dinv = d > 0.f ? 1.f/d : 0.f;
  sX[tid] = lrelu(nacc[base + tid]*dinv + b2[tid&31], 0.2f);
  __syncthreads();
  int ln = tid>>5, r = tid&31;
  if (r < RR){
    float a = bl[r];
#pragma unroll
    for (int kk=0;kk<HH;kk++) a += sX[ln*HH+kk]*sWl[kk*RR+r];
    out[(size_t)(blockIdx.x*8+ln)*RR + r] = lrelu(a, 0.01f);
  }
}

extern "C" void kernel_launch(void* const* d_in, const int* in_sizes, int n_in,
                              void* d_out, int out_size, void* d_ws, size_t ws_size,
                              hipStream_t stream){
  const float* price = (const float*)d_in[0];
  // d_in[1] = concept: unused (PreAttn path disabled in reference)
  const float* W_ih = (const float*)d_in[2];
  const float* W_hh = (const float*)d_in[3];
  const float* b_ih = (const float*)d_in[4];
  const float* b_hh = (const float*)d_in[5];
  const float* W1   = (const float*)d_in[6];
  const float* b1   = (const float*)d_in[7];
  const float* W2   = (const float*)d_in[8];
  const float* b2   = (const float*)d_in[9];
  const float* Wl   = (const float*)d_in[10];
  const float* bl   = (const float*)d_in[11];
  const int* nidx   = (const int*)d_in[12];
  const int* eidx   = (const int*)d_in[13];
  float* out = (float*)d_out;

  // ws layout (13.008 MB, proven size): xw | nacc | degD | degB
  float* ws   = (float*)d_ws;
  float* xw   = ws;                 // N*32
  float* nacc = ws + 1600000;       // N*32
  float* degD = ws + 3200000;       // 50000
  float* degB = ws + 3250000;       // 2000
  float* eacc = out;                // NE*32 = 64000 floats in d_out; dead before fin_final

  // one memset: nacc+degD+degB contiguous. eacc zeroed inside gru_mfma.
  hipMemsetAsync(nacc, 0, (1600000+52000)*sizeof(float), stream);

  gru_mfma<<<3125, 64, 0, stream>>>(price, W_ih, W_hh, b_ih, b_hh, W1, xw, eacc);

  // conv1 (xw = lrelu(hT)@W1^T fused in GRU epilogue; degrees counted in scat_e)
  scat_e<true><<<18750, 256, 0, stream>>>(xw, nidx, eidx, eacc, degD, degB);
  scat_n<<<18750, 256, 0, stream>>>(eacc, degB, nidx, eidx, nacc);
  finmm<<<6250, 256, 0, stream>>>(nacc, degD, b1, W2, xw, eacc);   // x1 -> @W2 -> xw; nacc,eacc := 0

  // conv2
  scat_e<false><<<18750, 256, 0, stream>>>(xw, nidx, eidx, eacc, degD, degB);
  scat_n<<<18750, 256, 0, stream>>>(eacc, degB, nidx, eidx, nacc);
  fin_final<<<6250, 256, 0, stream>>>(nacc, degD, b2, Wl, bl, out);
}